// Round 1
// baseline (1924.646 us; speedup 1.0000x reference)
//
#include <hip/hip_runtime.h>

#define TT   512
#define BT   8
#define NH1  100
#define NH2  60
#define NH3  30

// LDS layout (float offsets). Strides: W rows padded to multiples of 4 floats,
// chosen so row-start banks are distinct across the lanes that read them.
#define OFF_WHH1 0            // [100][100]
#define OFF_WIH2 10000        // [60][100]
#define OFF_WHH2 16000        // [60][60]
#define OFF_WIH3 19600        // [30][60]
#define OFF_WHH3 21400        // [30][36]  (k>=30 zero)
#define OFF_WO1  22480        // [10][36]  (k>=30 zero)
#define OFF_WIH1 22840        // [100][2]
#define OFF_WO2  23040        // [2][10] (+4 pad)
#define OFF_B1   23064        // 100  (b_ih1+b_hh1)
#define OFF_B2   23164        // 60
#define OFF_B3   23224        // 30 (+2 pad)
#define OFF_BO1  23256        // 10 (+2 pad)
#define OFF_BO2  23268        // 2 (+2 pad)
#define OFF_H1   23272        // [2][8][100] ping-pong
#define OFF_H2   24872        // [2][8][60]
#define OFF_H3   25832        // [2][8][36]  (k>=30 zero)
#define OFF_O    26408        // [8][12] head stage-1 buffer
#define OFF_X    26504        // [8][512][2] staged input
#define SMEM_FLOATS 34696     // 138784 B < 160 KiB

__device__ __forceinline__ float fast_tanh(float z) {
    z = fminf(15.f, fmaxf(-15.f, z));
    float e = __expf(2.f * z);                       // v_exp_f32 path
    return (e - 1.f) * __builtin_amdgcn_rcpf(e + 1.f);
}

#define DOT4(acc, wv, hv) do { \
    acc = fmaf((wv).x, (hv).x, acc); \
    acc = fmaf((wv).y, (hv).y, acc); \
    acc = fmaf((wv).z, (hv).z, acc); \
    acc = fmaf((wv).w, (hv).w, acc); } while (0)

__global__ __launch_bounds__(512)
void rnn3_fused(const float* __restrict__ xg,
                const float* __restrict__ Wih1, const float* __restrict__ Whh1,
                const float* __restrict__ bih1, const float* __restrict__ bhh1,
                const float* __restrict__ Wih2, const float* __restrict__ Whh2,
                const float* __restrict__ bih2, const float* __restrict__ bhh2,
                const float* __restrict__ Wih3, const float* __restrict__ Whh3,
                const float* __restrict__ bih3, const float* __restrict__ bhh3,
                const float* __restrict__ Wo1,  const float* __restrict__ bo1,
                const float* __restrict__ Wo2,  const float* __restrict__ bo2,
                float* __restrict__ outg)
{
    extern __shared__ __align__(16) float S[];
    const int tid = threadIdx.x;
    const int bbase = blockIdx.x * BT;

    // ---- stage: zero padded/state regions, then fill weights/x ----
    for (int i = tid; i < OFF_X - OFF_WHH3; i += 512) S[OFF_WHH3 + i] = 0.f;
    __syncthreads();
    for (int i = tid; i < NH1*NH1; i += 512) S[OFF_WHH1 + i] = Whh1[i];
    for (int i = tid; i < NH2*NH1; i += 512) S[OFF_WIH2 + i] = Wih2[i];
    for (int i = tid; i < NH2*NH2; i += 512) S[OFF_WHH2 + i] = Whh2[i];
    for (int i = tid; i < NH3*NH2; i += 512) S[OFF_WIH3 + i] = Wih3[i];
    for (int i = tid; i < NH3*NH3; i += 512) { int r = i / NH3, c = i - r*NH3; S[OFF_WHH3 + r*36 + c] = Whh3[i]; }
    for (int i = tid; i < 10*NH3;  i += 512) { int r = i / NH3, c = i - r*NH3; S[OFF_WO1  + r*36 + c] = Wo1[i]; }
    for (int i = tid; i < NH1*2;   i += 512) S[OFF_WIH1 + i] = Wih1[i];
    for (int i = tid; i < 20;      i += 512) S[OFF_WO2 + i] = Wo2[i];
    for (int i = tid; i < NH1;     i += 512) S[OFF_B1 + i] = bih1[i] + bhh1[i];
    for (int i = tid; i < NH2;     i += 512) S[OFF_B2 + i] = bih2[i] + bhh2[i];
    for (int i = tid; i < NH3;     i += 512) S[OFF_B3 + i] = bih3[i] + bhh3[i];
    for (int i = tid; i < 10;      i += 512) S[OFF_BO1 + i] = bo1[i];
    for (int i = tid; i < 2;       i += 512) S[OFF_BO2 + i] = bo2[i];
    for (int i = tid; i < BT*TT*2; i += 512) S[OFF_X + i] = xg[(size_t)bbase * (TT*2) + i];
    __syncthreads();

    const int j1 = tid >> 2;          // 0..127 (active < 100)
    const int ba = (tid & 3) * 2;     // batch pair {ba, ba+1}
    const int j2 = tid >> 3;          // 0..63 (L2 active < 60, L3 active < 30)
    const int bb = tid & 7;

    int p = 0;
    for (int t = 0; t < TT; ++t, p ^= 1) {
        const int q = p ^ 1;

        // ---------- phase 1: layer 1 (tids<400) | head stage-2 for t-2 (tids 480..495) ----------
        if (j1 < NH1) {
            const float* w  = S + OFF_WHH1 + j1 * NH1;
            const float* ha = S + OFF_H1 + p * (BT*NH1) + ba * NH1;
            const float* hb = ha + NH1;
            const float wx0 = S[OFF_WIH1 + j1*2];
            const float wx1 = S[OFF_WIH1 + j1*2 + 1];
            const float bias = S[OFF_B1 + j1];
            const float* xa = S + OFF_X + ba * (TT*2) + t*2;
            const float* xb = xa + (TT*2);
            float acc0 = fmaf(xa[0], wx0, fmaf(xa[1], wx1, bias));
            float acc1 = fmaf(xb[0], wx0, fmaf(xb[1], wx1, bias));
            #pragma unroll 5
            for (int k = 0; k < NH1; k += 4) {
                const float4 wv = *(const float4*)(w + k);
                const float4 va = *(const float4*)(ha + k);
                const float4 vb = *(const float4*)(hb + k);
                DOT4(acc0, wv, va);
                DOT4(acc1, wv, vb);
            }
            S[OFF_H1 + q*(BT*NH1) + ba*NH1 + j1]     = fast_tanh(acc0);
            S[OFF_H1 + q*(BT*NH1) + (ba+1)*NH1 + j1] = fast_tanh(acc1);
        } else if (tid >= 480 && tid < 496 && t >= 2) {
            const int v = (tid - 480) >> 3, ob = (tid - 480) & 7;
            float acc = S[OFF_BO2 + v];
            #pragma unroll
            for (int u = 0; u < 10; ++u)
                acc = fmaf(S[OFF_WO2 + v*10 + u], S[OFF_O + ob*12 + u], acc);
            outg[((size_t)(bbase + ob) * TT + (t - 2)) * 2 + v] = acc;
        }
        __syncthreads();

        // ---------- phase 2: layer 2 (tids<480) ----------
        if (tid < 480) {
            float acc = S[OFF_B2 + j2];
            const float* w = S + OFF_WIH2 + j2 * NH1;
            const float* h = S + OFF_H1 + q*(BT*NH1) + bb * NH1;   // h1 new
            #pragma unroll 5
            for (int k = 0; k < NH1; k += 4) {
                const float4 wv = *(const float4*)(w + k);
                const float4 hv = *(const float4*)(h + k);
                DOT4(acc, wv, hv);
            }
            const float* w2 = S + OFF_WHH2 + j2 * NH2;
            const float* h2 = S + OFF_H2 + p*(BT*NH2) + bb * NH2;  // h2 old
            #pragma unroll 5
            for (int k = 0; k < NH2; k += 4) {
                const float4 wv = *(const float4*)(w2 + k);
                const float4 hv = *(const float4*)(h2 + k);
                DOT4(acc, wv, hv);
            }
            S[OFF_H2 + q*(BT*NH2) + bb*NH2 + j2] = fast_tanh(acc);
        }
        __syncthreads();

        // ---------- phase 3: layer 3 (tids<240) | head stage-1 for t-1 (tids 256..335) ----------
        if (tid < 240) {
            const int j3 = j2;  // < 30
            float acc = S[OFF_B3 + j3];
            const float* w = S + OFF_WIH3 + j3 * NH2;
            const float* h = S + OFF_H2 + q*(BT*NH2) + bb * NH2;   // h2 new
            #pragma unroll 5
            for (int k = 0; k < NH2; k += 4) {
                const float4 wv = *(const float4*)(w + k);
                const float4 hv = *(const float4*)(h + k);
                DOT4(acc, wv, hv);
            }
            const float* w2 = S + OFF_WHH3 + j3 * 36;
            const float* h3 = S + OFF_H3 + p*(BT*36) + bb * 36;    // h3 old
            #pragma unroll
            for (int k = 0; k < 32; k += 4) {                      // zero-padded to 32
                const float4 wv = *(const float4*)(w2 + k);
                const float4 hv = *(const float4*)(h3 + k);
                DOT4(acc, wv, hv);
            }
            S[OFF_H3 + q*(BT*36) + bb*36 + j3] = fast_tanh(acc);
        } else if (tid >= 256 && tid < 336 && t >= 1) {
            const int u = (tid - 256) >> 3, hb = (tid - 256) & 7;
            float acc = S[OFF_BO1 + u];
            const float* w = S + OFF_WO1 + u * 36;
            const float* h = S + OFF_H3 + p*(BT*36) + hb * 36;     // h3 state t-1
            #pragma unroll
            for (int k = 0; k < 32; k += 4) {
                const float4 wv = *(const float4*)(w + k);
                const float4 hv = *(const float4*)(h + k);
                DOT4(acc, wv, hv);
            }
            S[OFF_O + hb*12 + u] = acc;
        }
        __syncthreads();
    }

    // ---- epilogue: p == 0 here; o_lds holds o(510); h3 state 511 in buffer 0 ----
    if (tid >= 480 && tid < 496) {
        const int v = (tid - 480) >> 3, ob = (tid - 480) & 7;
        float acc = S[OFF_BO2 + v];
        #pragma unroll
        for (int u = 0; u < 10; ++u)
            acc = fmaf(S[OFF_WO2 + v*10 + u], S[OFF_O + ob*12 + u], acc);
        outg[((size_t)(bbase + ob) * TT + 510) * 2 + v] = acc;
    }
    __syncthreads();
    if (tid >= 256 && tid < 336) {
        const int u = (tid - 256) >> 3, hb = (tid - 256) & 7;
        float acc = S[OFF_BO1 + u];
        const float* w = S + OFF_WO1 + u * 36;
        const float* h = S + OFF_H3 + hb * 36;                     // buffer 0 = state 511
        #pragma unroll
        for (int k = 0; k < 32; k += 4) {
            const float4 wv = *(const float4*)(w + k);
            const float4 hv = *(const float4*)(h + k);
            DOT4(acc, wv, hv);
        }
        S[OFF_O + hb*12 + u] = acc;
    }
    __syncthreads();
    if (tid >= 480 && tid < 496) {
        const int v = (tid - 480) >> 3, ob = (tid - 480) & 7;
        float acc = S[OFF_BO2 + v];
        #pragma unroll
        for (int u = 0; u < 10; ++u)
            acc = fmaf(S[OFF_WO2 + v*10 + u], S[OFF_O + ob*12 + u], acc);
        outg[((size_t)(bbase + ob) * TT + 511) * 2 + v] = acc;
    }
}

extern "C" void kernel_launch(void* const* d_in, const int* in_sizes, int n_in,
                              void* d_out, int out_size, void* d_ws, size_t ws_size,
                              hipStream_t stream) {
    (void)in_sizes; (void)n_in; (void)d_ws; (void)ws_size; (void)out_size;
    const float* x     = (const float*)d_in[0];
    const float* W_ih1 = (const float*)d_in[1];
    const float* W_hh1 = (const float*)d_in[2];
    const float* b_ih1 = (const float*)d_in[3];
    const float* b_hh1 = (const float*)d_in[4];
    const float* W_ih2 = (const float*)d_in[5];
    const float* W_hh2 = (const float*)d_in[6];
    const float* b_ih2 = (const float*)d_in[7];
    const float* b_hh2 = (const float*)d_in[8];
    const float* W_ih3 = (const float*)d_in[9];
    const float* W_hh3 = (const float*)d_in[10];
    const float* b_ih3 = (const float*)d_in[11];
    const float* b_hh3 = (const float*)d_in[12];
    const float* W_o1  = (const float*)d_in[13];
    const float* b_o1  = (const float*)d_in[14];
    const float* W_o2  = (const float*)d_in[15];
    const float* b_o2  = (const float*)d_in[16];
    float* out = (float*)d_out;

    const size_t smem = (size_t)SMEM_FLOATS * sizeof(float);   // 138784 B
    hipFuncSetAttribute((const void*)rnn3_fused,
                        hipFuncAttributeMaxDynamicSharedMemorySize, (int)smem);
    rnn3_fused<<<2048 / BT, 512, smem, stream>>>(
        x, W_ih1, W_hh1, b_ih1, b_hh1,
        W_ih2, W_hh2, b_ih2, b_hh2,
        W_ih3, W_hh3, b_ih3, b_hh3,
        W_o1, b_o1, W_o2, b_o2, out);
}

// Round 2
// 469.440 us; speedup vs baseline: 4.0999x; 4.0999x over previous
//
#include <hip/hip_runtime.h>

typedef _Float16 v8hf __attribute__((ext_vector_type(8)));
typedef float    v4f  __attribute__((ext_vector_type(4)));

#define MFMA16(a, b, c) __builtin_amdgcn_mfma_f32_16x16x32_f16((a), (b), (c), 0, 0, 0)

#define TT 512
#define BT 16          // batch rows per workgroup (= MFMA M)

// LDS row strides (f16 units), padded so (stride_bytes/4 * row) mod 32 spreads banks:
// h1: 136 f16 = 272 B = 68 dw -> 4*row mod 32 (2-way, free)
// h2:  72 f16 = 144 B = 36 dw -> 4*row mod 32
// h3:  40 f16 =  80 B = 20 dw -> 20*row mod 32, distinct over 8 rows
__shared__ __align__(16) _Float16 h1b[2][BT][136];
__shared__ __align__(16) _Float16 h2b[2][BT][72];
__shared__ __align__(16) _Float16 h3b[2][BT][40];
__shared__ __align__(16) _Float16 xst[TT][2 * BT];   // [t][b*2+c]

__device__ __forceinline__ float fast_tanh(float z) {
    z = fminf(15.f, fmaxf(-15.f, z));
    float e = __expf(2.f * z);
    return (e - 1.f) * __builtin_amdgcn_rcpf(e + 1.f);
}

__global__ __launch_bounds__(512)
void rnn3_mfma(const float* __restrict__ xg,
               const float* __restrict__ Wih1, const float* __restrict__ Whh1,
               const float* __restrict__ bih1, const float* __restrict__ bhh1,
               const float* __restrict__ Wih2, const float* __restrict__ Whh2,
               const float* __restrict__ bih2, const float* __restrict__ bhh2,
               const float* __restrict__ Wih3, const float* __restrict__ Whh3,
               const float* __restrict__ bih3, const float* __restrict__ bhh3,
               const float* __restrict__ Wo1,  const float* __restrict__ bo1,
               const float* __restrict__ Wo2,  const float* __restrict__ bo2,
               float* __restrict__ outg)
{
    const int tid   = threadIdx.x;
    const int lane  = tid & 63;
    const int wid   = tid >> 6;       // wave 0..7
    const int col   = lane & 15;      // MFMA 16-lane index (A-row / B-col / C-col)
    const int g     = lane >> 4;      // k-group 0..3
    const int bbase = blockIdx.x * BT;

    // ---------------- init: zero state buffers, stage x ----------------
    {
        _Float16* z1 = &h1b[0][0][0];
        for (int i = tid; i < 2 * BT * 136; i += 512) z1[i] = (_Float16)0.f;
        _Float16* z2 = &h2b[0][0][0];
        for (int i = tid; i < 2 * BT * 72; i += 512) z2[i] = (_Float16)0.f;
        _Float16* z3 = &h3b[0][0][0];
        for (int i = tid; i < 2 * BT * 40; i += 512) z3[i] = (_Float16)0.f;
        for (int i = tid; i < BT * TT * 2; i += 512) {
            float v = xg[(size_t)bbase * (TT * 2) + i];
            int b = i >> 10, r = i & 1023, t = r >> 1, c = r & 1;
            xst[t][b * 2 + c] = (_Float16)v;
        }
    }

    // ---------------- load weight B-fragments into registers ----------------
    // B-frag convention: value at (lane, e) = W[j][k] with j = 16*tile + col,
    // k = kt*32 + g*8 + e. (Any HW K-permutation cancels since A uses same map.)
    v8hf wb1[4]  = {};
    v8hf wb2a[4] = {}, wb2b[2] = {};
    v8hf wb3a[2] = {}, wb3b    = {};
    v8hf wbo     = {};
    float bias1 = 0.f, bias2 = 0.f, bias3 = 0.f, beff = 0.f;

    if (wid < 7) {                                   // L1: j-tile = wid
        const int j = 16 * wid + col;
        #pragma unroll
        for (int kt = 0; kt < 4; ++kt)
            #pragma unroll
            for (int e = 0; e < 8; ++e) {
                const int k = kt * 32 + g * 8 + e;
                float v = 0.f;
                if (j < 100) {
                    if (k < 100)      v = Whh1[j * 100 + k];
                    else if (k < 102) v = Wih1[j * 2 + (k - 100)];
                }
                wb1[kt][e] = (_Float16)v;
            }
        if (j < 100) bias1 = bih1[j] + bhh1[j];
    }
    if (wid < 4) {                                   // L2: j-tile = wid
        const int j = 16 * wid + col;
        #pragma unroll
        for (int kt = 0; kt < 4; ++kt)
            #pragma unroll
            for (int e = 0; e < 8; ++e) {
                const int k = kt * 32 + g * 8 + e;
                float v = (j < 60 && k < 100) ? Wih2[j * 100 + k] : 0.f;
                wb2a[kt][e] = (_Float16)v;
            }
        #pragma unroll
        for (int kt = 0; kt < 2; ++kt)
            #pragma unroll
            for (int e = 0; e < 8; ++e) {
                const int k = kt * 32 + g * 8 + e;
                float v = (j < 60 && k < 60) ? Whh2[j * 60 + k] : 0.f;
                wb2b[kt][e] = (_Float16)v;
            }
        if (j < 60) bias2 = bih2[j] + bhh2[j];
    }
    if (wid < 2) {                                   // L3: j-tile = wid
        const int j = 16 * wid + col;
        #pragma unroll
        for (int kt = 0; kt < 2; ++kt)
            #pragma unroll
            for (int e = 0; e < 8; ++e) {
                const int k = kt * 32 + g * 8 + e;
                float v = (j < 30 && k < 60) ? Wih3[j * 60 + k] : 0.f;
                wb3a[kt][e] = (_Float16)v;
            }
        #pragma unroll
        for (int e = 0; e < 8; ++e) {
            const int k = g * 8 + e;
            float v = (j < 30 && k < 30) ? Whh3[j * 30 + k] : 0.f;
            wb3b[e] = (_Float16)v;
        }
        if (j < 30) bias3 = bih3[j] + bhh3[j];
    }
    if (wid == 7) {                                  // head: W_eff = Wo2 @ Wo1 (2x30)
        #pragma unroll
        for (int e = 0; e < 8; ++e) {
            const int k = g * 8 + e;
            float v = 0.f;
            if (col < 2 && k < 30) {
                #pragma unroll
                for (int u = 0; u < 10; ++u) v += Wo2[col * 10 + u] * Wo1[u * 30 + k];
            }
            wbo[e] = (_Float16)v;
        }
        if (col < 2) {
            float bv = bo2[col];
            #pragma unroll
            for (int u = 0; u < 10; ++u) bv += Wo2[col * 10 + u] * bo1[u];
            beff = bv;
        }
    }

    __syncthreads();
    if (tid < BT) {   // x_0 into parity-0 h1 buffer at k=100..101
        *(unsigned*)&h1b[0][tid][100] = *(const unsigned*)&xst[0][tid * 2];
    }
    __syncthreads();

    // ---------------- recurrent loop ----------------
    auto step = [&](int t, int p, int q) {
        // ---- P1: L1 (waves 0-6) | head for t-1 + x-copy (wave 7) ----
        if (wid < 7) {
            const _Float16* hp = &h1b[p][col][0];
            v8hf a0 = *(const v8hf*)(hp +       g * 8);
            v8hf a1 = *(const v8hf*)(hp +  32 + g * 8);
            v8hf a2 = *(const v8hf*)(hp +  64 + g * 8);
            v8hf a3 = *(const v8hf*)(hp +  96 + g * 8);
            v4f acc0 = {bias1, bias1, bias1, bias1};
            v4f acc1 = {0.f, 0.f, 0.f, 0.f};
            acc0 = MFMA16(a0, wb1[0], acc0);
            acc1 = MFMA16(a1, wb1[1], acc1);
            acc0 = MFMA16(a2, wb1[2], acc0);
            acc1 = MFMA16(a3, wb1[3], acc1);
            const int j = 16 * wid + col;
            if (j < 100) {
                #pragma unroll
                for (int i = 0; i < 4; ++i)
                    h1b[q][4 * g + i][j] = (_Float16)fast_tanh(acc0[i] + acc1[i]);
            }
        } else {
            if (t >= 1) {
                const _Float16* hp = &h3b[p][col][0];
                v8hf a = *(const v8hf*)(hp + g * 8);
                v4f o = {beff, beff, beff, beff};
                o = MFMA16(a, wbo, o);
                if (col < 2) {
                    #pragma unroll
                    for (int i = 0; i < 4; ++i)
                        outg[(((size_t)(bbase + 4 * g + i)) * TT + (t - 1)) * 2 + col] = o[i];
                }
            }
            if (t < TT - 1 && lane < BT)   // stage x_{t+1} into h1b[q][b][100..101]
                *(unsigned*)&h1b[q][lane][100] = *(const unsigned*)&xst[t + 1][lane * 2];
        }
        __syncthreads();

        // ---- P2: L2 (waves 0-3) ----
        if (wid < 4) {
            const _Float16* hp1 = &h1b[q][col][0];
            const _Float16* hp2 = &h2b[p][col][0];
            v8hf a0 = *(const v8hf*)(hp1 +       g * 8);
            v8hf a1 = *(const v8hf*)(hp1 +  32 + g * 8);
            v8hf a2 = *(const v8hf*)(hp1 +  64 + g * 8);
            v8hf a3 = *(const v8hf*)(hp1 +  96 + g * 8);
            v8hf b0 = *(const v8hf*)(hp2 +       g * 8);
            v8hf b1 = *(const v8hf*)(hp2 +  32 + g * 8);
            v4f acc0 = {bias2, bias2, bias2, bias2};
            v4f acc1 = {0.f, 0.f, 0.f, 0.f};
            acc0 = MFMA16(a0, wb2a[0], acc0);
            acc1 = MFMA16(a1, wb2a[1], acc1);
            acc0 = MFMA16(a2, wb2a[2], acc0);
            acc1 = MFMA16(a3, wb2a[3], acc1);
            acc0 = MFMA16(b0, wb2b[0], acc0);
            acc1 = MFMA16(b1, wb2b[1], acc1);
            const int j = 16 * wid + col;
            if (j < 60) {
                #pragma unroll
                for (int i = 0; i < 4; ++i)
                    h2b[q][4 * g + i][j] = (_Float16)fast_tanh(acc0[i] + acc1[i]);
            }
        }
        __syncthreads();

        // ---- P3: L3 (waves 0-1) ----
        if (wid < 2) {
            const _Float16* hp2 = &h2b[q][col][0];
            const _Float16* hp3 = &h3b[p][col][0];
            v8hf a0 = *(const v8hf*)(hp2 +      g * 8);
            v8hf a1 = *(const v8hf*)(hp2 + 32 + g * 8);
            v8hf b0 = *(const v8hf*)(hp3 +      g * 8);
            v4f acc0 = {bias3, bias3, bias3, bias3};
            v4f acc1 = {0.f, 0.f, 0.f, 0.f};
            acc0 = MFMA16(a0, wb3a[0], acc0);
            acc1 = MFMA16(a1, wb3a[1], acc1);
            acc0 = MFMA16(b0, wb3b, acc0);
            const int j = 16 * wid + col;
            if (j < 30) {
                #pragma unroll
                for (int i = 0; i < 4; ++i)
                    h3b[q][4 * g + i][j] = (_Float16)fast_tanh(acc0[i] + acc1[i]);
            }
        }
        __syncthreads();
    };

    for (int t = 0; t < TT; ++t) step(t, t & 1, (t & 1) ^ 1);

    // epilogue: head for t=511 (h3(511) sits in parity 0)
    if (wid == 7) {
        const _Float16* hp = &h3b[0][col][0];
        v8hf a = *(const v8hf*)(hp + g * 8);
        v4f o = {beff, beff, beff, beff};
        o = MFMA16(a, wbo, o);
        if (col < 2) {
            #pragma unroll
            for (int i = 0; i < 4; ++i)
                outg[(((size_t)(bbase + 4 * g + i)) * TT + (TT - 1)) * 2 + col] = o[i];
        }
    }
}

extern "C" void kernel_launch(void* const* d_in, const int* in_sizes, int n_in,
                              void* d_out, int out_size, void* d_ws, size_t ws_size,
                              hipStream_t stream) {
    (void)in_sizes; (void)n_in; (void)d_ws; (void)ws_size; (void)out_size;
    const float* x     = (const float*)d_in[0];
    const float* W_ih1 = (const float*)d_in[1];
    const float* W_hh1 = (const float*)d_in[2];
    const float* b_ih1 = (const float*)d_in[3];
    const float* b_hh1 = (const float*)d_in[4];
    const float* W_ih2 = (const float*)d_in[5];
    const float* W_hh2 = (const float*)d_in[6];
    const float* b_ih2 = (const float*)d_in[7];
    const float* b_hh2 = (const float*)d_in[8];
    const float* W_ih3 = (const float*)d_in[9];
    const float* W_hh3 = (const float*)d_in[10];
    const float* b_ih3 = (const float*)d_in[11];
    const float* b_hh3 = (const float*)d_in[12];
    const float* W_o1  = (const float*)d_in[13];
    const float* b_o1  = (const float*)d_in[14];
    const float* W_o2  = (const float*)d_in[15];
    const float* b_o2  = (const float*)d_in[16];
    float* out = (float*)d_out;

    rnn3_mfma<<<2048 / BT, 512, 0, stream>>>(
        x, W_ih1, W_hh1, b_ih1, b_hh1,
        W_ih2, W_hh2, b_ih2, b_hh2,
        W_ih3, W_hh3, b_ih3, b_hh3,
        W_o1, b_o1, W_o2, b_o2, out);
}

// Round 3
// 314.586 us; speedup vs baseline: 6.1180x; 1.4922x over previous
//
#include <hip/hip_runtime.h>

typedef _Float16 v8hf __attribute__((ext_vector_type(8)));
typedef float    v4f  __attribute__((ext_vector_type(4)));

#define MFMA16(a, b, c) __builtin_amdgcn_mfma_f32_16x16x32_f16((a), (b), (c), 0, 0, 0)

#define TT 512
#define BT 16      // batch rows per workgroup (= MFMA M)
#define NTH 448    // 7 waves

// h1 k-layout: 0..99 = h1, 100..111 = fake neurons (always 0 in, 0 weights),
//              112..113 = x_t, 114..135 = zero pad.
__shared__ __align__(16) _Float16 h1b[2][BT][136];
__shared__ __align__(16) _Float16 h2b[2][BT][72];
__shared__ __align__(16) _Float16 h3b[2][BT][40];
__shared__ __align__(16) _Float16 xst[TT][2 * BT];   // [t][b*2+c]

__device__ __forceinline__ float fast_tanh(float z) {
    z = fminf(15.f, fmaxf(-15.f, z));
    float e = __expf(2.f * z);
    return 1.f - 2.f * __builtin_amdgcn_rcpf(e + 1.f);
}

__global__ __launch_bounds__(NTH)
void rnn3_pipe(const float* __restrict__ xg,
               const float* __restrict__ Wih1, const float* __restrict__ Whh1,
               const float* __restrict__ bih1, const float* __restrict__ bhh1,
               const float* __restrict__ Wih2, const float* __restrict__ Whh2,
               const float* __restrict__ bih2, const float* __restrict__ bhh2,
               const float* __restrict__ Wih3, const float* __restrict__ Whh3,
               const float* __restrict__ bih3, const float* __restrict__ bhh3,
               const float* __restrict__ Wo1,  const float* __restrict__ bo1,
               const float* __restrict__ Wo2,  const float* __restrict__ bo2,
               float* __restrict__ outg)
{
    const int tid   = threadIdx.x;
    const int lane  = tid & 63;
    const int wid   = tid >> 6;       // wave 0..6
    const int col   = lane & 15;      // MFMA 16-lane index
    const int g     = lane >> 4;      // k-group 0..3
    const int bbase = blockIdx.x * BT;

    // ---------------- init: zero state buffers, stage x ----------------
    {
        _Float16* z1 = &h1b[0][0][0];
        for (int i = tid; i < 2 * BT * 136; i += NTH) z1[i] = (_Float16)0.f;
        _Float16* z2 = &h2b[0][0][0];
        for (int i = tid; i < 2 * BT * 72; i += NTH) z2[i] = (_Float16)0.f;
        _Float16* z3 = &h3b[0][0][0];
        for (int i = tid; i < 2 * BT * 40; i += NTH) z3[i] = (_Float16)0.f;
        for (int i = tid; i < BT * TT * 2; i += NTH) {
            float v = xg[(size_t)bbase * (TT * 2) + i];
            int b = i >> 10, r = i & 1023, t = r >> 1, c = r & 1;
            xst[t][b * 2 + c] = (_Float16)v;
        }
    }

    // ---------------- weight fragments (registers) ----------------
    // B-frag convention: (lane,e) = W[j][k], j = 16*tile + col, k = kt*32 + g*8 + e.
    v8hf f0[4] = {}, f1[4] = {}, f2[2] = {}, f3[2] = {};
    v8hf wbo = {};
    float bA = 0.f, bB = 0.f, beff = 0.f;

    auto ldW = [&](const float* W, int rows, int cols, int j, int kt) -> v8hf {
        v8hf r;
        #pragma unroll
        for (int e = 0; e < 8; ++e) {
            const int k = kt * 32 + g * 8 + e;
            float v = (j < rows && k < cols) ? W[j * cols + k] : 0.f;
            r[e] = (_Float16)v;
        }
        return r;
    };
    auto ldW1 = [&](int j, int kt) -> v8hf {     // Whh1 (k<100) + x weights at k=112,113
        v8hf r;
        #pragma unroll
        for (int e = 0; e < 8; ++e) {
            const int k = kt * 32 + g * 8 + e;
            float v = 0.f;
            if (j < 100) {
                if (k < 100)            v = Whh1[j * 100 + k];
                else if (k == 112)      v = Wih1[j * 2];
                else if (k == 113)      v = Wih1[j * 2 + 1];
            }
            r[e] = (_Float16)v;
        }
        return r;
    };

    if (wid < 3) {                                     // L1 tiles 2w, 2w+1
        const int ja = 16 * (2 * wid) + col, jb = ja + 16;
        #pragma unroll
        for (int kt = 0; kt < 4; ++kt) { f0[kt] = ldW1(ja, kt); f1[kt] = ldW1(jb, kt); }
        bA = (ja < 100) ? bih1[ja] + bhh1[ja] : 0.f;
        bB = (jb < 100) ? bih1[jb] + bhh1[jb] : 0.f;
    } else if (wid == 3) {                             // L1 tile 6 + head
        const int j = 96 + col;
        #pragma unroll
        for (int kt = 0; kt < 4; ++kt) f0[kt] = ldW1(j, kt);
        bA = (j < 100) ? bih1[j] + bhh1[j] : 0.f;
        #pragma unroll
        for (int e = 0; e < 8; ++e) {                  // W_eff = Wo2 @ Wo1 (2 x 30)
            const int k = g * 8 + e;
            float v = 0.f;
            if (col < 2 && k < 30) {
                #pragma unroll
                for (int u = 0; u < 10; ++u) v += Wo2[col * 10 + u] * Wo1[u * 30 + k];
            }
            wbo[e] = (_Float16)v;
        }
        if (col < 2) {
            float bv = bo2[col];
            #pragma unroll
            for (int u = 0; u < 10; ++u) bv += Wo2[col * 10 + u] * bo1[u];
            beff = bv;
        }
    } else if (wid < 6) {                              // L2 tiles 2(w-4), 2(w-4)+1
        const int ja = 16 * (2 * (wid - 4)) + col, jb = ja + 16;
        #pragma unroll
        for (int kt = 0; kt < 4; ++kt) { f0[kt] = ldW(Wih2, 60, 100, ja, kt); f1[kt] = ldW(Wih2, 60, 100, jb, kt); }
        #pragma unroll
        for (int kt = 0; kt < 2; ++kt) { f2[kt] = ldW(Whh2, 60, 60, ja, kt); f3[kt] = ldW(Whh2, 60, 60, jb, kt); }
        bA = (ja < 60) ? bih2[ja] + bhh2[ja] : 0.f;
        bB = (jb < 60) ? bih2[jb] + bhh2[jb] : 0.f;
    } else {                                           // L3 tiles 0,1
        const int ja = col, jb = col + 16;
        #pragma unroll
        for (int kt = 0; kt < 2; ++kt) { f0[kt] = ldW(Wih3, 30, 60, ja, kt); f1[kt] = ldW(Wih3, 30, 60, jb, kt); }
        f2[0] = ldW(Whh3, 30, 30, ja, 0);
        f3[0] = ldW(Whh3, 30, 30, jb, 0);
        bA = (ja < 30) ? bih3[ja] + bhh3[ja] : 0.f;
        bB = (jb < 30) ? bih3[jb] + bhh3[jb] : 0.f;
    }

    __syncthreads();
    if (tid < BT)   // x_0 into h1 buffer parity 0 at k=112..113
        *(unsigned*)&h1b[0][tid][112] = *(const unsigned*)&xst[0][tid * 2];
    __syncthreads();

    // ---------------- pipelined loop: one barrier per phase ----------------
    // phase s: L1(s) | L2(s-1) | L3(s-2) | head(s-3)
    for (int s = 0; s < TT + 3; ++s) {
        const int rp = s & 1, wp = rp ^ 1;

        if (wid < 3) {
            if (s < TT) {
                const _Float16* hp = &h1b[rp][col][0];
                v8hf a0 = *(const v8hf*)(hp +      g * 8);
                v8hf a1 = *(const v8hf*)(hp + 32 + g * 8);
                v8hf a2 = *(const v8hf*)(hp + 64 + g * 8);
                v8hf a3 = *(const v8hf*)(hp + 96 + g * 8);
                v4f p0 = {bA, bA, bA, bA}, q0 = {0.f, 0.f, 0.f, 0.f};
                v4f p1 = {bB, bB, bB, bB}, q1 = {0.f, 0.f, 0.f, 0.f};
                p0 = MFMA16(a0, f0[0], p0); q0 = MFMA16(a1, f0[1], q0);
                p0 = MFMA16(a2, f0[2], p0); q0 = MFMA16(a3, f0[3], q0);
                p1 = MFMA16(a0, f1[0], p1); q1 = MFMA16(a1, f1[1], q1);
                p1 = MFMA16(a2, f1[2], p1); q1 = MFMA16(a3, f1[3], q1);
                const int j0 = 32 * wid + col;
                #pragma unroll
                for (int i = 0; i < 4; ++i) {
                    h1b[wp][4 * g + i][j0]      = (_Float16)fast_tanh(p0[i] + q0[i]);
                    h1b[wp][4 * g + i][j0 + 16] = (_Float16)fast_tanh(p1[i] + q1[i]);
                }
            }
        } else if (wid == 3) {
            if (s < TT - 1 && lane < BT)   // stage x_{s+1}
                *(unsigned*)&h1b[wp][lane][112] = *(const unsigned*)&xst[s + 1][2 * lane];
            if (s < TT) {
                const _Float16* hp = &h1b[rp][col][0];
                v8hf a0 = *(const v8hf*)(hp +      g * 8);
                v8hf a1 = *(const v8hf*)(hp + 32 + g * 8);
                v8hf a2 = *(const v8hf*)(hp + 64 + g * 8);
                v8hf a3 = *(const v8hf*)(hp + 96 + g * 8);
                v4f p0 = {bA, bA, bA, bA}, q0 = {0.f, 0.f, 0.f, 0.f};
                p0 = MFMA16(a0, f0[0], p0); q0 = MFMA16(a1, f0[1], q0);
                p0 = MFMA16(a2, f0[2], p0); q0 = MFMA16(a3, f0[3], q0);
                #pragma unroll
                for (int i = 0; i < 4; ++i)
                    h1b[wp][4 * g + i][96 + col] = (_Float16)fast_tanh(p0[i] + q0[i]);
            }
            if (s >= 3) {                  // head for t = s-3, h3(s-3) in h3b[rp]
                const _Float16* hp = &h3b[rp][col][0];
                v8hf a = *(const v8hf*)(hp + g * 8);
                v4f o = {beff, beff, beff, beff};
                o = MFMA16(a, wbo, o);
                if (col < 2) {
                    #pragma unroll
                    for (int i = 0; i < 4; ++i)
                        outg[(((size_t)(bbase + 4 * g + i)) * TT + (s - 3)) * 2 + col] = o[i];
                }
            }
        } else if (wid < 6) {
            if (s >= 1 && s <= TT) {       // L2 for t = s-1: h1(s-1) in h1b[rp], h2(s-2) in h2b[wp]
                const _Float16* hp1 = &h1b[rp][col][0];
                const _Float16* hp2 = &h2b[wp][col][0];
                v8hf a0 = *(const v8hf*)(hp1 +      g * 8);
                v8hf a1 = *(const v8hf*)(hp1 + 32 + g * 8);
                v8hf a2 = *(const v8hf*)(hp1 + 64 + g * 8);
                v8hf a3 = *(const v8hf*)(hp1 + 96 + g * 8);
                v8hf c0 = *(const v8hf*)(hp2 +      g * 8);
                v8hf c1 = *(const v8hf*)(hp2 + 32 + g * 8);
                v4f p0 = {bA, bA, bA, bA}, q0 = {0.f, 0.f, 0.f, 0.f};
                v4f p1 = {bB, bB, bB, bB}, q1 = {0.f, 0.f, 0.f, 0.f};
                p0 = MFMA16(a0, f0[0], p0); q0 = MFMA16(a1, f0[1], q0);
                p0 = MFMA16(a2, f0[2], p0); q0 = MFMA16(a3, f0[3], q0);
                p0 = MFMA16(c0, f2[0], p0); q0 = MFMA16(c1, f2[1], q0);
                p1 = MFMA16(a0, f1[0], p1); q1 = MFMA16(a1, f1[1], q1);
                p1 = MFMA16(a2, f1[2], p1); q1 = MFMA16(a3, f1[3], q1);
                p1 = MFMA16(c0, f3[0], p1); q1 = MFMA16(c1, f3[1], q1);
                const int j0 = 32 * (wid - 4) + col;
                #pragma unroll
                for (int i = 0; i < 4; ++i) {
                    h2b[rp][4 * g + i][j0]      = (_Float16)fast_tanh(p0[i] + q0[i]);
                    h2b[rp][4 * g + i][j0 + 16] = (_Float16)fast_tanh(p1[i] + q1[i]);
                }
            }
        } else {
            if (s >= 2 && s <= TT + 1) {   // L3 for t = s-2: h2(s-2) in h2b[wp], h3(s-3) in h3b[rp]
                const _Float16* hp2 = &h2b[wp][col][0];
                const _Float16* hp3 = &h3b[rp][col][0];
                v8hf a0 = *(const v8hf*)(hp2 +      g * 8);
                v8hf a1 = *(const v8hf*)(hp2 + 32 + g * 8);
                v8hf c0 = *(const v8hf*)(hp3 +      g * 8);
                v4f p0 = {bA, bA, bA, bA}, q0 = {0.f, 0.f, 0.f, 0.f};
                v4f p1 = {bB, bB, bB, bB}, q1 = {0.f, 0.f, 0.f, 0.f};
                p0 = MFMA16(a0, f0[0], p0); q0 = MFMA16(a1, f0[1], q0);
                p0 = MFMA16(c0, f2[0], p0);
                p1 = MFMA16(a0, f1[0], p1); q1 = MFMA16(a1, f1[1], q1);
                p1 = MFMA16(c0, f3[0], p1);
                #pragma unroll
                for (int i = 0; i < 4; ++i) {
                    h3b[wp][4 * g + i][col]      = (_Float16)fast_tanh(p0[i] + q0[i]);
                    h3b[wp][4 * g + i][col + 16] = (_Float16)fast_tanh(p1[i] + q1[i]);
                }
            }
        }
        __syncthreads();
    }
}

extern "C" void kernel_launch(void* const* d_in, const int* in_sizes, int n_in,
                              void* d_out, int out_size, void* d_ws, size_t ws_size,
                              hipStream_t stream) {
    (void)in_sizes; (void)n_in; (void)d_ws; (void)ws_size; (void)out_size;
    const float* x     = (const float*)d_in[0];
    const float* W_ih1 = (const float*)d_in[1];
    const float* W_hh1 = (const float*)d_in[2];
    const float* b_ih1 = (const float*)d_in[3];
    const float* b_hh1 = (const float*)d_in[4];
    const float* W_ih2 = (const float*)d_in[5];
    const float* W_hh2 = (const float*)d_in[6];
    const float* b_ih2 = (const float*)d_in[7];
    const float* b_hh2 = (const float*)d_in[8];
    const float* W_ih3 = (const float*)d_in[9];
    const float* W_hh3 = (const float*)d_in[10];
    const float* b_ih3 = (const float*)d_in[11];
    const float* b_hh3 = (const float*)d_in[12];
    const float* W_o1  = (const float*)d_in[13];
    const float* b_o1  = (const float*)d_in[14];
    const float* W_o2  = (const float*)d_in[15];
    const float* b_o2  = (const float*)d_in[16];
    float* out = (float*)d_out;

    rnn3_pipe<<<2048 / BT, NTH, 0, stream>>>(
        x, W_ih1, W_hh1, b_ih1, b_hh1,
        W_ih2, W_hh2, b_ih2, b_hh2,
        W_ih3, W_hh3, b_ih3, b_hh3,
        W_o1, b_o1, W_o2, b_o2, out);
}